// Round 7
// baseline (166.841 us; speedup 1.0000x reference)
//
#include <hip/hip_runtime.h>

// out[h,k,v] = 0.95*M[h,k,v] + sum_{b,s} rho[b,s]*K[b,s,h,k]*V[b,s,h,v]
// B=4, S=4096 (ROWS=16384), H=16, Dk=Dv=64.
//
// R7 = R6's bf16-MFMA main loop + ATOMIC-FREE epilogue.
// Evidence: R1/R3/R5/R6 all floor at ~50-75 us with every pipe idle; WRITE_SIZE
// == 16.4 MB of memory-side fp32 atomic RMWs in every round (R5 replays: 16.78MB
// writes, 0 fetch). Device-scope atomics serialize at the memory side (per-XCD
// L2s non-coherent) -> ~40 us invariant floor. Fix: each block streams its 16KB
// partial to d_ws (plain coalesced stores), then reduce_ws sums 64 slices/head
// and fuses 0.95*M. Atomic fallback only if ws_size < 16 MB.

typedef __bf16  bf16x8  __attribute__((ext_vector_type(8)));
typedef float   floatx4 __attribute__((ext_vector_type(4)));

constexpr int HH = 16;
constexpr int DK = 64;
constexpr int DV = 64;
constexpr int ROWS = 16384;
constexpr int NSLICE = 64;            // grid.x
constexpr int RPB = ROWS / NSLICE;    // 256 rows per block
constexpr int RPW = RPB / 4;          // 64 rows per wave
constexpr int TS  = 32;               // s-rows per MFMA step (K-dim)
constexpr int NT  = RPW / TS;         // 2 tiles per wave
constexpr int PAD = 65;               // LDS row stride (floats)
constexpr float DECAY = 0.95f;
constexpr size_t WS_NEED = (size_t)NSLICE * HH * DK * DV * 4;   // 16 MiB

__global__ __launch_bounds__(256) void init_out(const float* __restrict__ mem,
                                                float* __restrict__ out) {
    int i = blockIdx.x * 256 + threadIdx.x;
    out[i] = DECAY * mem[i];
}

// use_ws==true : write block partial to ws[(chunk*HH+h)*4096 + i] (plain stores)
// use_ws==false: atomicAdd into out (pre-initialized by init_out)
__global__ __launch_bounds__(256) void accum(const float* __restrict__ keys,
                                             const float* __restrict__ values,
                                             const float* __restrict__ rho,
                                             float* __restrict__ out,
                                             float* __restrict__ ws,
                                             int use_ws) {
    __shared__ float red[2][64 * PAD];   // 33,280 B, epilogue only

    const int t    = threadIdx.x;
    const int w    = t >> 6;
    const int lane = t & 63;
    const int m15  = lane & 15;
    const int q    = lane >> 4;
    const int h    = blockIdx.y;
    const int row0 = blockIdx.x * RPB + w * RPW;

    floatx4 acc[4][4];
    #pragma unroll
    for (int i = 0; i < 4; ++i)
        #pragma unroll
        for (int j = 0; j < 4; ++j)
            acc[i][j] = (floatx4){0.f, 0.f, 0.f, 0.f};

    #pragma unroll
    for (int tile = 0; tile < NT; ++tile) {
        const int s0 = row0 + tile * TS;
        const int sl = s0 + q * 8;            // this lane's first s

        float4 r0 = *(const float4*)(rho + sl);
        float4 r1 = *(const float4*)(rho + sl + 4);
        float rv[8] = {r0.x, r0.y, r0.z, r0.w, r1.x, r1.y, r1.z, r1.w};

        const float* kbase = keys   + ((size_t)sl * HH + h) * DK + m15;
        const float* vbase = values + ((size_t)sl * HH + h) * DV + m15;

        bf16x8 af[4], bfr[4];
        #pragma unroll
        for (int mt = 0; mt < 4; ++mt) {
            #pragma unroll
            for (int j = 0; j < 8; ++j) {
                float x = kbase[(size_t)j * (HH * DK) + mt * 16] * rv[j];
                af[mt][j] = (__bf16)x;
            }
        }
        #pragma unroll
        for (int nt = 0; nt < 4; ++nt) {
            #pragma unroll
            for (int j = 0; j < 8; ++j) {
                float x = vbase[(size_t)j * (HH * DV) + nt * 16];
                bfr[nt][j] = (__bf16)x;
            }
        }

        #pragma unroll
        for (int mt = 0; mt < 4; ++mt)
            #pragma unroll
            for (int nt = 0; nt < 4; ++nt)
                acc[mt][nt] = __builtin_amdgcn_mfma_f32_16x16x32_bf16(
                    af[mt], bfr[nt], acc[mt][nt], 0, 0, 0);
    }

    // ---- pairwise-reduce 4 wave partials in LDS ----
    // C/D mapping: element [row = mt*16 + q*4 + r][col = nt*16 + m15]
    float* dst = red[w & 1];
    if (w < 2) {
        #pragma unroll
        for (int mt = 0; mt < 4; ++mt)
            #pragma unroll
            for (int nt = 0; nt < 4; ++nt)
                #pragma unroll
                for (int r = 0; r < 4; ++r)
                    dst[(mt * 16 + q * 4 + r) * PAD + nt * 16 + m15] = acc[mt][nt][r];
    }
    __syncthreads();
    if (w >= 2) {
        #pragma unroll
        for (int mt = 0; mt < 4; ++mt)
            #pragma unroll
            for (int nt = 0; nt < 4; ++nt)
                #pragma unroll
                for (int r = 0; r < 4; ++r) {
                    float* p = &dst[(mt * 16 + q * 4 + r) * PAD + nt * 16 + m15];
                    *p = *p + acc[mt][nt][r];
                }
    }
    __syncthreads();

    if (use_ws) {
        // plain coalesced streaming stores of the 4096-float block partial
        float* wsp = ws + ((size_t)blockIdx.x * HH + h) * (DK * DV);
        #pragma unroll
        for (int i = 0; i < 16; ++i) {
            int idx = i * 256 + t;
            int rr = idx >> 6, cc = idx & 63;
            wsp[idx] = red[0][rr * PAD + cc] + red[1][rr * PAD + cc];
        }
    } else {
        float* o = out + h * (DK * DV);
        #pragma unroll
        for (int i = 0; i < 16; ++i) {
            int idx = i * 256 + t;
            int rr = idx >> 6, cc = idx & 63;
            atomicAdd(o + idx, red[0][rr * PAD + cc] + red[1][rr * PAD + cc]);
        }
    }
}

// out[o] = 0.95*mem[o] + sum_c ws[(c*HH+h)*4096 + i],  o = h*4096+i
// grid: 64 blocks x 256 threads; each thread one float4 (16384 float4 total)
__global__ __launch_bounds__(256) void reduce_ws(const float* __restrict__ mem,
                                                 const float* __restrict__ ws,
                                                 float* __restrict__ out) {
    const int o4 = blockIdx.x * 256 + threadIdx.x;   // float4 index
    const int o  = o4 * 4;
    const int h  = o >> 12;          // 4096 floats per head
    const int i  = o & 4095;

    float4 m = *(const float4*)(mem + o);
    float4 acc = make_float4(DECAY * m.x, DECAY * m.y, DECAY * m.z, DECAY * m.w);

    const float* p = ws + (size_t)h * (DK * DV) + i;
    #pragma unroll 8
    for (int c = 0; c < NSLICE; ++c) {
        float4 v = *(const float4*)(p + (size_t)c * HH * DK * DV);
        acc.x += v.x; acc.y += v.y; acc.z += v.z; acc.w += v.w;
    }
    *(float4*)(out + o) = acc;
}

extern "C" void kernel_launch(void* const* d_in, const int* in_sizes, int n_in,
                              void* d_out, int out_size, void* d_ws, size_t ws_size,
                              hipStream_t stream) {
    const float* mem    = (const float*)d_in[0];  // (H, Dk, Dv)
    const float* keys   = (const float*)d_in[1];  // (B, S, H, Dk)
    const float* values = (const float*)d_in[2];  // (B, S, H, Dv)
    const float* rho    = (const float*)d_in[3];  // (B, S)
    float* out = (float*)d_out;                   // (H, Dk, Dv)
    float* ws  = (float*)d_ws;

    dim3 grid(NSLICE, HH);
    if (ws_size >= WS_NEED) {
        accum<<<grid, dim3(256), 0, stream>>>(keys, values, rho, out, ws, 1);
        reduce_ws<<<dim3(64), dim3(256), 0, stream>>>(mem, ws, out);
    } else {
        init_out<<<dim3((HH * DK * DV) / 256), dim3(256), 0, stream>>>(mem, out);
        accum<<<grid, dim3(256), 0, stream>>>(keys, values, rho, out, ws, 0);
    }
}

// Round 8
// 163.452 us; speedup vs baseline: 1.0207x; 1.0207x over previous
//
#include <hip/hip_runtime.h>

// out[h,k,v] = 0.95*M[h,k,v] + sum_{b,s} rho[b,s]*K[b,s,h,k]*V[b,s,h,v]
// B=4, S=4096 (ROWS=16384), H=16, Dk=Dv=64.
//
// R8: fix R6/R7's VMEM serialization (132 dependent scalar loads/wave ->
// ~900cyc each, 1 in flight => 50us). Per tile each lane now issues 16
// INDEPENDENT coalesced float4 loads into register arrays, converts to
// rho-folded bf16, stages a wave-private LDS tile (row-major bf16,
// 136B row stride), then gathers MFMA fragments from LDS (120cyc, hidden).
// Tile t+1 loads issue before tile t's fragment reads (overlap). Zero
// main-loop barriers. Epilogue: pairwise LDS reduce + streaming stores to
// d_ws + reduce_ws kernel (atomic fallback if ws too small).

typedef __bf16  bf16x8  __attribute__((ext_vector_type(8)));
typedef float   floatx4 __attribute__((ext_vector_type(4)));

constexpr int HH = 16;
constexpr int DK = 64;
constexpr int DV = 64;
constexpr int ROWS = 16384;
constexpr int NSLICE = 64;            // grid.x
constexpr int RPB = ROWS / NSLICE;    // 256 rows per block
constexpr int RPW = RPB / 4;          // 64 rows per wave
constexpr int TSR = 32;               // s-rows per staged tile (MFMA K-dim)
constexpr int SPW = 68;               // LDS row stride in ushorts (136 B)
constexpr int WAVE_DW = 2 * TSR * SPW / 2;   // dwords per wave area (K+V) = 2176
constexpr int PAD = 65;               // epilogue LDS row stride (floats)
constexpr float DECAY = 0.95f;
constexpr size_t WS_NEED = (size_t)NSLICE * HH * DK * DV * 4;   // 16 MiB

__global__ __launch_bounds__(256) void init_out(const float* __restrict__ mem,
                                                float* __restrict__ out) {
    int i = blockIdx.x * 256 + threadIdx.x;
    out[i] = DECAY * mem[i];
}

__device__ __forceinline__ unsigned int pk2(float a, float b) {
    __bf16 lo = (__bf16)a, hi = (__bf16)b;
    unsigned short ul = __builtin_bit_cast(unsigned short, lo);
    unsigned short uh = __builtin_bit_cast(unsigned short, hi);
    return (unsigned int)ul | ((unsigned int)uh << 16);
}

__global__ __launch_bounds__(256) void accum(const float* __restrict__ keys,
                                             const float* __restrict__ values,
                                             const float* __restrict__ rho,
                                             float* __restrict__ out,
                                             float* __restrict__ ws,
                                             int use_ws) {
    // 34,816 B: staging = 4 waves x 2176 dwords (K-tile + V-tile, bf16,
    // row stride 136 B); epilogue reuses it as red[2][64*65] fp32.
    __shared__ __align__(16) unsigned char smem_raw[34816];

    const int t    = threadIdx.x;
    const int w    = t >> 6;
    const int lane = t & 63;
    const int m15  = lane & 15;
    const int q    = lane >> 4;
    const int h    = blockIdx.y;
    const int row0 = blockIdx.x * RPB + w * RPW;

    unsigned short* kb = (unsigned short*)smem_raw + (size_t)w * WAVE_DW * 2;
    unsigned short* vb = kb + TSR * SPW;

    floatx4 acc[4][4];
    #pragma unroll
    for (int i = 0; i < 4; ++i)
        #pragma unroll
        for (int j = 0; j < 4; ++j)
            acc[i][j] = (floatx4){0.f, 0.f, 0.f, 0.f};

    const size_t rstride = (size_t)HH * DK;   // floats between consecutive s
    // lane stages rows s_loc = q*8 + i (i=0..7), col quad m15*4
    const float* kbase = keys   + ((size_t)row0 * HH + h) * DK + m15 * 4;
    const float* vbase = values + ((size_t)row0 * HH + h) * DV + m15 * 4;

    // --- issue tile T's 18 independent loads into register arrays ---
    #define LOADT(T, GK, GV, R0, R1) do {                                     \
        const float* kp_ = kbase + (size_t)((T) * TSR + q * 8) * rstride;     \
        const float* vp_ = vbase + (size_t)((T) * TSR + q * 8) * rstride;     \
        _Pragma("unroll")                                                     \
        for (int i_ = 0; i_ < 8; ++i_)                                        \
            GK[i_] = *(const float4*)(kp_ + (size_t)i_ * rstride);            \
        _Pragma("unroll")                                                     \
        for (int i_ = 0; i_ < 8; ++i_)                                        \
            GV[i_] = *(const float4*)(vp_ + (size_t)i_ * rstride);            \
        R0 = *(const float4*)(rho + row0 + (T) * TSR + q * 8);                \
        R1 = *(const float4*)(rho + row0 + (T) * TSR + q * 8 + 4);            \
    } while (0)

    // --- convert (rho-folded K) to bf16, write wave-private LDS tile ---
    #define STAGE(GK, GV, R0, R1) do {                                        \
        float rr_[8] = {R0.x, R0.y, R0.z, R0.w, R1.x, R1.y, R1.z, R1.w};      \
        _Pragma("unroll")                                                     \
        for (int i_ = 0; i_ < 8; ++i_) {                                      \
            float4 x_ = GK[i_]; float rv_ = rr_[i_];                          \
            uint2 pk_; pk_.x = pk2(x_.x * rv_, x_.y * rv_);                   \
            pk_.y = pk2(x_.z * rv_, x_.w * rv_);                              \
            *(uint2*)(kb + (q * 8 + i_) * SPW + m15 * 4) = pk_;               \
            float4 y_ = GV[i_];                                               \
            uint2 pv_; pv_.x = pk2(y_.x, y_.y); pv_.y = pk2(y_.z, y_.w);      \
            *(uint2*)(vb + (q * 8 + i_) * SPW + m15 * 4) = pv_;               \
        }                                                                     \
    } while (0)

    // --- gather fragments from LDS (conflict-free u16 col-walks), MFMA ---
    #define FRAGMM() do {                                                     \
        bf16x8 af_[4], bv_[4];                                                \
        _Pragma("unroll")                                                     \
        for (int mt_ = 0; mt_ < 4; ++mt_)                                     \
            _Pragma("unroll")                                                 \
            for (int j_ = 0; j_ < 8; ++j_) {                                  \
                af_[mt_][j_] = ((const __bf16*)kb)[(q * 8 + j_) * SPW + m15 + 16 * mt_]; \
                bv_[mt_][j_] = ((const __bf16*)vb)[(q * 8 + j_) * SPW + m15 + 16 * mt_]; \
            }                                                                 \
        _Pragma("unroll")                                                     \
        for (int mt_ = 0; mt_ < 4; ++mt_)                                     \
            _Pragma("unroll")                                                 \
            for (int nt_ = 0; nt_ < 4; ++nt_)                                 \
                acc[mt_][nt_] = __builtin_amdgcn_mfma_f32_16x16x32_bf16(      \
                    af_[mt_], bv_[nt_], acc[mt_][nt_], 0, 0, 0);              \
    } while (0)

    {
        float4 gk[8], gv[8], r0, r1;
        float4 hk[8], hv[8], s0, s1;
        LOADT(0, gk, gv, r0, r1);
        STAGE(gk, gv, r0, r1);       // waits tile-0 loads; LDS writes issue
        LOADT(1, hk, hv, s0, s1);    // tile-1 loads in flight during...
        FRAGMM();                    // ...tile-0 fragment reads + MFMA
        STAGE(hk, hv, s0, s1);       // in-order DS: writes can't pass reads
        FRAGMM();
    }
    #undef LOADT
    #undef STAGE
    #undef FRAGMM

    // ---- epilogue: pairwise-reduce 4 wave partials in LDS, stream out ----
    __syncthreads();   // staging areas retired before reuse as reduction buf
    float* red0 = (float*)smem_raw;
    float* red1 = red0 + 64 * PAD;
    float* dst  = (w & 1) ? red1 : red0;

    // C/D mapping: element [row = mt*16 + q*4 + r][col = nt*16 + m15]
    if (w < 2) {
        #pragma unroll
        for (int mt = 0; mt < 4; ++mt)
            #pragma unroll
            for (int nt = 0; nt < 4; ++nt)
                #pragma unroll
                for (int r = 0; r < 4; ++r)
                    dst[(mt * 16 + q * 4 + r) * PAD + nt * 16 + m15] = acc[mt][nt][r];
    }
    __syncthreads();
    if (w >= 2) {
        #pragma unroll
        for (int mt = 0; mt < 4; ++mt)
            #pragma unroll
            for (int nt = 0; nt < 4; ++nt)
                #pragma unroll
                for (int r = 0; r < 4; ++r) {
                    float* p = &dst[(mt * 16 + q * 4 + r) * PAD + nt * 16 + m15];
                    *p = *p + acc[mt][nt][r];
                }
    }
    __syncthreads();

    if (use_ws) {
        float* wsp = ws + ((size_t)blockIdx.x * HH + h) * (DK * DV);
        #pragma unroll
        for (int i = 0; i < 16; ++i) {
            int idx = i * 256 + t;
            int rr = idx >> 6, cc = idx & 63;
            wsp[idx] = red0[rr * PAD + cc] + red1[rr * PAD + cc];
        }
    } else {
        float* o = out + h * (DK * DV);
        #pragma unroll
        for (int i = 0; i < 16; ++i) {
            int idx = i * 256 + t;
            int rr = idx >> 6, cc = idx & 63;
            atomicAdd(o + idx, red0[rr * PAD + cc] + red1[rr * PAD + cc]);
        }
    }
}

// out[o] = 0.95*mem[o] + sum_c ws[(c*HH+h)*4096 + i],  o = h*4096+i
__global__ __launch_bounds__(256) void reduce_ws(const float* __restrict__ mem,
                                                 const float* __restrict__ ws,
                                                 float* __restrict__ out) {
    const int o4 = blockIdx.x * 256 + threadIdx.x;   // float4 index
    const int o  = o4 * 4;
    const int h  = o >> 12;
    const int i  = o & 4095;

    float4 m = *(const float4*)(mem + o);
    float4 acc = make_float4(DECAY * m.x, DECAY * m.y, DECAY * m.z, DECAY * m.w);

    const float* p = ws + (size_t)h * (DK * DV) + i;
    #pragma unroll 8
    for (int c = 0; c < NSLICE; ++c) {
        float4 v = *(const float4*)(p + (size_t)c * HH * DK * DV);
        acc.x += v.x; acc.y += v.y; acc.z += v.z; acc.w += v.w;
    }
    *(float4*)(out + o) = acc;
}

extern "C" void kernel_launch(void* const* d_in, const int* in_sizes, int n_in,
                              void* d_out, int out_size, void* d_ws, size_t ws_size,
                              hipStream_t stream) {
    const float* mem    = (const float*)d_in[0];  // (H, Dk, Dv)
    const float* keys   = (const float*)d_in[1];  // (B, S, H, Dk)
    const float* values = (const float*)d_in[2];  // (B, S, H, Dv)
    const float* rho    = (const float*)d_in[3];  // (B, S)
    float* out = (float*)d_out;                   // (H, Dk, Dv)
    float* ws  = (float*)d_ws;

    dim3 grid(NSLICE, HH);
    if (ws_size >= WS_NEED) {
        accum<<<grid, dim3(256), 0, stream>>>(keys, values, rho, out, ws, 1);
        reduce_ws<<<dim3(64), dim3(256), 0, stream>>>(mem, ws, out);
    } else {
        init_out<<<dim3((HH * DK * DV) / 256), dim3(256), 0, stream>>>(mem, out);
        accum<<<grid, dim3(256), 0, stream>>>(keys, values, rho, out, ws, 0);
    }
}